// Round 6
// baseline (85.855 us; speedup 1.0000x reference)
//
#include <hip/hip_runtime.h>

#define TPB 256

typedef __attribute__((ext_vector_type(8))) short short8;
typedef __attribute__((ext_vector_type(4))) float f32x4;

__device__ __forceinline__ unsigned f2bf_pk(float a, float b) {
  return ((__float_as_uint(a) + 0x8000u) >> 16) | ((__float_as_uint(b) + 0x8000u) & 0xffff0000u);
}
__device__ __forceinline__ float bflo(unsigned v) { return __uint_as_float(v << 16); }
__device__ __forceinline__ float bfhi(unsigned v) { return __uint_as_float(v & 0xffff0000u); }

// Cross-lane half-swap adds on the VALU pipe. MUST use the builtins, not
// inline asm: v_permlane*_swap has a VALU-write -> permlane-read hazard
// needing compiler-inserted wait states (Round-3's hand asm violated it ->
// nondeterministic corruption; builtins verified correct in R4/R5).
__device__ __forceinline__ float swap16_add(float v) {
  auto r = __builtin_amdgcn_permlane16_swap(__float_as_uint(v), __float_as_uint(v), false, false);
  return __uint_as_float(r[0]) + __uint_as_float(r[1]);  // == v + v[lane^16]
}
__device__ __forceinline__ float swap32_add(float v) {
  auto r = __builtin_amdgcn_permlane32_swap(__float_as_uint(v), __float_as_uint(v), false, false);
  return __uint_as_float(r[0]) + __uint_as_float(r[1]);  // == v + v[lane^32]
}

// ---- single kernel, NO workspace. The harness re-poisons d_ws (256 MiB
// fill, ~40 us at HBM peak) inside the timed region every iteration; that
// fill was half our total. The Wq A-fragment table is now built per-oo in
// LDS cooperatively (256 thr x 9 iters: float4 read -> f2bf_pk -> b64
// write = same bytes/rounding as the old prep table), then consumed by the
// R0-proven wqbuf MFMA read pattern. Deletes prep_kernel + its launch gap
// + all d_ws use. LDS 39408 B -> still 4 blocks/CU (16 waves/CU).
__global__ __launch_bounds__(TPB, 4) void dppc9_kernel(
    const float* __restrict__ x, const float* __restrict__ Wp,
    const float* __restrict__ bp, float* __restrict__ out) {
  // [r 0..2][ww 0..65][c 0..31 pad40], bf16; stride 40 shorts = 80 B
  __shared__ __align__(16) unsigned short xrow2[3 * 66 * 40];   // 15840 B
  __shared__ __align__(16) char wqls[18432];                    // 18432 B
  __shared__ __align__(16) float bp_s[4 * 288];                 // 4608 B
  __shared__ __align__(16) float Wb_s[4 * 32];                  // 512 B
  __shared__ float bias4[4];                                    // 39408 total

  const int tid = threadIdx.x;
  const int bid = blockIdx.x;
  const int og  = bid & 7;      // couts og*4 .. og*4+3  (== XCD id)
  const int t   = bid >> 3;
  const int b   = t >> 6;
  const int h   = t & 63;

  // per-thread constants for the cooperative A-stage (9 exact iterations:
  // 2304 half-entries / 256 threads). Entry e = rt*64+lane covers Wp row
  // row(o) = o*288 + (m16>>2)*72 + rt*4 + (m16&3), floats [kq*8, kq*8+8).
  // Half hf stages floats [kq*8+hf*4 .. +4) as two f2bf_pk words -> the
  // bit-exact layout the old prep_kernel produced.

#define STAGE_WQ(O_)                                                        \
  do {                                                                      \
    const int obase_ = (O_) * 9216;                                         \
    for (int i = tid; i < 2304; i += TPB) {                                 \
      const int e_ = i >> 1, hf_ = i & 1;                                   \
      const int rt_ = e_ >> 6, lane_ = e_ & 63;                             \
      const int m16_ = lane_ & 15, kq_ = lane_ >> 4;                        \
      const int row_ = (m16_ >> 2) * 72 + rt_ * 4 + (m16_ & 3);             \
      const float4 f_ = *(const float4*)(Wp + obase_ + row_ * 32 + kq_ * 8 + hf_ * 4); \
      *(uint2*)(wqls + (e_ << 4) + (hf_ << 3)) =                            \
          make_uint2(f2bf_pk(f_.x, f_.y), f2bf_pk(f_.z, f_.w));             \
    }                                                                       \
  } while (0)

  // prelude: side-halo zero words (disjoint from interior) + interior stage
  for (int i = tid; i < 120; i += TPB) {      // 6 (r,ww-halo) slots x 20 words
    int p = i / 20, w = i % 20;
    ((unsigned*)xrow2)[(((p >> 1) * 66 + ((p & 1) ? 65 : 0)) * 20) + w] = 0;
  }
  for (int i = tid; i < 1536; i += TPB) {     // r(3) x c4(8) x px(64)
    int px_ = i & 63, c4 = (i >> 6) & 7, r = i >> 9;
    int hh = h - 1 + r;
    unsigned w0 = 0, w1 = 0;
    if ((unsigned)hh < 64u) {
      const float* xp = x + ((b * 32 + c4 * 4) * 64 + hh) * 64 + px_;
      float f0 = xp[0], f1 = xp[4096], f2 = xp[8192], f3 = xp[12288];
      w0 = f2bf_pk(f0, f1);
      w1 = f2bf_pk(f2, f3);
    }
    uint2* dst = (uint2*)&xrow2[(r * 66 + 1 + px_) * 40 + c4 * 4];
    *dst = make_uint2(w0, w1);
  }
  for (int i = tid; i < 1152; i += TPB) bp_s[i] = bp[og * 1152 + i];
  if (tid < 128) Wb_s[tid] = Wp[(9216 + og * 4 + (tid >> 5)) * 32 + (tid & 31)];
  if (tid < 4) bias4[tid] = bp[9216 + og * 4 + tid];
  STAGE_WQ(og * 4);             // A-slice for oo=0, rides under the prelude
  __syncthreads();

  const int lane = tid & 63;
  const int wv   = tid >> 6;
  const int m16  = lane & 15, kq = lane >> 4;
  const int px   = wv * 16 + m16;

#pragma unroll 1
  for (int oo = 0; oo < 4; ++oo) {
    const int o = og * 4 + oo;

    // one b128 read serves: MFMA B-fragment, pass-B kk=4 tap, epilogue
    // center tap (all the same 16 B of xrow2).
    const uint4 cent = *(const uint4*)&xrow2[(66 + 1 + px) * 40 + kq * 8];
    const short8 bfrag = *(const short8*)&cent;

    // phase 1: 18 MFMAs, predictor bias folded into C-operand; A-frags from
    // LDS (R0-proven pattern: compiler interleaves ds_read/MFMA via lgkmcnt,
    // no spill). lane holds pred fp32 for idx=c8*9+k at px: acc[idx>>2][idx&3]
    f32x4 acc[18];
#pragma unroll
    for (int rt = 0; rt < 18; ++rt) {
      const short8 a = *(const short8*)(wqls + (rt * 64 + lane) * 16);
      const f32x4 bb = *(const f32x4*)&bp_s[oo * 288 + kq * 72 + rt * 4];
      acc[rt] = __builtin_amdgcn_mfma_f32_16x16x32_bf16(a, bfrag, bb, 0, 0, 0);
    }

    // cin-norm denominators: local partial + reduce across kq (bits 4,5)
    // on the VALU via permlane swaps (same FP order as the shfl chain).
    float rinv[9];
#pragma unroll
    for (int kk = 0; kk < 9; ++kk) rinv[kk] = 0.f;
#pragma unroll
    for (int c8 = 0; c8 < 8; ++c8)
#pragma unroll
      for (int kk = 0; kk < 9; ++kk) {
        const int idx = c8 * 9 + kk;
        const float v = acc[idx >> 2][idx & 3];
        rinv[kk] += v * v;
      }
#pragma unroll
    for (int kk = 0; kk < 9; ++kk) {
      float s = rinv[kk];
      s = swap16_add(s);
      s = swap32_add(s);
      rinv[kk] = rsqrtf(fmaxf(s, 1e-24f));  // == 1/max(sqrt(s),1e-12)
    }

    // pass B: per tap k one b128 patch read (kk=4 reuses cent), s2/dot
    // accumulated per c8; k-norm applied in the epilogue.
    float s2[8], dot[8];
#pragma unroll
    for (int c8 = 0; c8 < 8; ++c8) { s2[c8] = 0.f; dot[c8] = 0.f; }
#pragma unroll
    for (int kk = 0; kk < 9; ++kk) {
      const int kh = kk / 3, kw = kk - kh * 3;
      const uint4 tp = (kk == 4) ? cent
                                 : *(const uint4*)&xrow2[(kh * 66 + kw + px) * 40 + kq * 8];
      const float rv = rinv[kk];
#pragma unroll
      for (int c8 = 0; c8 < 8; ++c8) {
        const int idx = c8 * 9 + kk;
        const float tv = acc[idx >> 2][idx & 3] * rv;
        s2[c8] += tv * tv;
        const unsigned wd = ((const unsigned*)&tp)[c8 >> 1];
        const float pv = (c8 & 1) ? bfhi(wd) : bflo(wd);
        dot[c8] += tv * pv;
      }
    }

    // epilogue: combine per-c8, add dyn-bias partials, butterfly, store.
    const f32x4 wb0 = *(const f32x4*)&Wb_s[oo * 32 + kq * 8];
    const f32x4 wb1 = *(const f32x4*)&Wb_s[oo * 32 + kq * 8 + 4];
    float oacc = 0.f;
#pragma unroll
    for (int c8 = 0; c8 < 8; ++c8) {
      oacc += rsqrtf(fmaxf(s2[c8], 1e-24f)) * dot[c8];
      const unsigned wd = ((const unsigned*)&cent)[c8 >> 1];
      const float xc = (c8 & 1) ? bfhi(wd) : bflo(wd);
      const float wbv = (c8 < 4) ? wb0[c8] : wb1[c8 - 4];
      oacc += wbv * xc;
    }
    oacc = swap16_add(oacc);
    oacc = swap32_add(oacc);
    if (kq == 0)
      out[((b * 32 + o) * 64 + h) * 64 + px] = oacc + bias4[oo];

    // restage wqls for oo+1: all waves must be done reading (barrier),
    // then cooperative stage, then visibility barrier.
    if (oo < 3) {
      __syncthreads();
      STAGE_WQ(o + 1);
      __syncthreads();
    }
  }
#undef STAGE_WQ
}

extern "C" void kernel_launch(void* const* d_in, const int* in_sizes, int n_in,
                              void* d_out, int out_size, void* d_ws, size_t ws_size,
                              hipStream_t stream) {
  const float* x  = (const float*)d_in[0];
  const float* Wp = (const float*)d_in[1];
  const float* bp = (const float*)d_in[2];
  float* out = (float*)d_out;
  (void)d_ws; (void)ws_size;  // workspace intentionally unused (poison-fill lever)
  dppc9_kernel<<<1024, TPB, 0, stream>>>(x, Wp, bp, out);
}

// Round 7
// 81.807 us; speedup vs baseline: 1.0495x; 1.0495x over previous
//
#include <hip/hip_runtime.h>

#define TPB 256
#define WQ_BYTES 589824  // 32*18*64*8*2

typedef __attribute__((ext_vector_type(8))) short short8;
typedef __attribute__((ext_vector_type(4))) float f32x4;

__device__ __forceinline__ unsigned f2bf_pk(float a, float b) {
  return ((__float_as_uint(a) + 0x8000u) >> 16) | ((__float_as_uint(b) + 0x8000u) & 0xffff0000u);
}
__device__ __forceinline__ float bflo(unsigned v) { return __uint_as_float(v << 16); }
__device__ __forceinline__ float bfhi(unsigned v) { return __uint_as_float(v & 0xffff0000u); }

// NOTE: reductions use __shfl_xor (LDS pipe). The permlane16/32_swap VALU
// variant was measured SLOWER (R4/R5 ≈ +2 us): each permlane needs
// compiler-inserted hazard wait-states -> pure VALU bubbles, while the
// shfl chain overlaps under other waves. Do not re-introduce.

// ---- prep: permuted bf16 A-fragment table (row permute makes each lane's
// 18x4 accumulator exactly 8 cin x 9 k for one pixel) ----------------------
__global__ void prep_kernel(const float* __restrict__ Wp, unsigned* __restrict__ Wq) {
  int idx = blockIdx.x * blockDim.x + threadIdx.x;  // 147456 u32
  if (idx >= 32 * 18 * 64 * 4) return;
  int j2   = idx & 3;
  int lane = (idx >> 2) & 63;
  int rt   = (idx >> 8) % 18;
  int o    = (idx >> 8) / 18;
  int m16 = lane & 15, kq = lane >> 4;
  int row = o * 288 + (m16 >> 2) * 72 + rt * 4 + (m16 & 3);
  const float* src = Wp + row * 32 + kq * 8 + j2 * 2;
  Wq[idx] = f2bf_pk(src[0], src[1]);
}

// ---- main: 2048 blocks (og split 16 ways, 2 couts / 2 oo per block) =
// ~2 generations of 4 blocks/CU. The 1024-block one-generation layout ran
// all resident blocks in phase lockstep (identical phases simultaneously,
// exposed prelude/A-load latency, full tail); two generations stagger the
// phases — gen-2 preludes ride under gen-1 compute and the per-block tail
// halves. bid&7 == XCD id is preserved (same-og blocks stay one-XCD for
// A-slice L2 locality). A-fragments read directly from global Wq with the
// R2-verified sched_barrier-pinned 6-load/6-MFMA groups (spill-free).
template <bool USE_WQ>
__global__ __launch_bounds__(TPB, 4) void dppc9_kernel(
    const float* __restrict__ x, const float* __restrict__ Wp,
    const float* __restrict__ bp, const unsigned* __restrict__ Wq,
    float* __restrict__ out) {
  // [r 0..2][ww 0..65][c 0..31 pad40], bf16; stride 40 shorts = 80 B
  __shared__ __align__(16) unsigned short xrow2[3 * 66 * 40];   // 15840 B
  __shared__ __align__(16) float bp_s[2 * 288];                 // 2304 B
  __shared__ __align__(16) float Wb_s[2 * 32];                  // 256 B
  __shared__ float bias2[2];                                    // ~18.5 KB total

  const int tid = threadIdx.x;
  const int bid = blockIdx.x;
  const int og  = bid & 15;     // couts og*2 .. og*2+1  (bid&7 == XCD id)
  const int t   = bid >> 4;
  const int b   = t >> 6;
  const int h   = t & 63;

  const char* wq_g = (const char*)Wq + (size_t)(og * 2) * 18432;

  // prelude: side-halo zero words (disjoint from interior) + interior stage
  for (int i = tid; i < 120; i += TPB) {      // 6 (r,ww-halo) slots x 20 words
    int p = i / 20, w = i % 20;
    ((unsigned*)xrow2)[(((p >> 1) * 66 + ((p & 1) ? 65 : 0)) * 20) + w] = 0;
  }
  for (int i = tid; i < 1536; i += TPB) {     // r(3) x c4(8) x px(64)
    int px_ = i & 63, c4 = (i >> 6) & 7, r = i >> 9;
    int hh = h - 1 + r;
    unsigned w0 = 0, w1 = 0;
    if ((unsigned)hh < 64u) {
      const float* xp = x + ((b * 32 + c4 * 4) * 64 + hh) * 64 + px_;
      float f0 = xp[0], f1 = xp[4096], f2 = xp[8192], f3 = xp[12288];
      w0 = f2bf_pk(f0, f1);
      w1 = f2bf_pk(f2, f3);
    }
    uint2* dst = (uint2*)&xrow2[(r * 66 + 1 + px_) * 40 + c4 * 4];
    *dst = make_uint2(w0, w1);
  }
  for (int i = tid; i < 576; i += TPB) bp_s[i] = bp[og * 576 + i];
  if (tid < 64) Wb_s[tid] = Wp[(9216 + og * 2 + (tid >> 5)) * 32 + (tid & 31)];
  if (tid < 2) bias2[tid] = bp[9216 + og * 2 + tid];
  __syncthreads();   // the ONLY barrier

  const int lane = tid & 63;
  const int wv   = tid >> 6;
  const int m16  = lane & 15, kq = lane >> 4;
  const int px   = wv * 16 + m16;

#pragma unroll 1
  for (int oo = 0; oo < 2; ++oo) {
    const int o = og * 2 + oo;

    // one b128 read serves: MFMA B-fragment, pass-B kk=4 tap, epilogue
    // center tap (all the same 16 B of xrow2).
    const uint4 cent = *(const uint4*)&xrow2[(66 + 1 + px) * 40 + kq * 8];
    const short8 bfrag = *(const short8*)&cent;

    // phase 1: 18 MFMAs; strict 6-load / 6-MFMA groups pinned by
    // sched_barrier(0) (keeps at most 24 A-VGPRs in flight; an
    // unconstrained hoist of all 18 loads spills — R1).
    f32x4 acc[18];
    if (USE_WQ) {
      const char* ap = wq_g + ((oo * 1152 + lane) << 4);
#pragma unroll
      for (int g = 0; g < 3; ++g) {
        short8 a6[6];
#pragma unroll
        for (int j = 0; j < 6; ++j)
          a6[j] = *(const short8*)(ap + (((g * 6 + j) << 10)));
        __builtin_amdgcn_sched_barrier(0);
#pragma unroll
        for (int j = 0; j < 6; ++j) {
          const int rt = g * 6 + j;
          const f32x4 bb = *(const f32x4*)&bp_s[oo * 288 + kq * 72 + rt * 4];
          acc[rt] = __builtin_amdgcn_mfma_f32_16x16x32_bf16(a6[j], bfrag, bb, 0, 0, 0);
        }
        __builtin_amdgcn_sched_barrier(0);
      }
    } else {
      const float* ab = Wp + (o * 288 + (m16 >> 2) * 72 + (m16 & 3)) * 32 + kq * 8;
#pragma unroll
      for (int rt = 0; rt < 18; ++rt) {
        const float* ap = ab + rt * 4 * 32;
        float4 a0 = *(const float4*)ap;
        float4 a1 = *(const float4*)(ap + 4);
        union { short8 v; unsigned u[4]; } af;
        af.u[0] = f2bf_pk(a0.x, a0.y);
        af.u[1] = f2bf_pk(a0.z, a0.w);
        af.u[2] = f2bf_pk(a1.x, a1.y);
        af.u[3] = f2bf_pk(a1.z, a1.w);
        const f32x4 bb = *(const f32x4*)&bp_s[oo * 288 + kq * 72 + rt * 4];
        acc[rt] = __builtin_amdgcn_mfma_f32_16x16x32_bf16(af.v, bfrag, bb, 0, 0, 0);
      }
    }

    // cin-norm denominators: local partial + butterfly across kq (bits 4,5)
    float rinv[9];
#pragma unroll
    for (int kk = 0; kk < 9; ++kk) rinv[kk] = 0.f;
#pragma unroll
    for (int c8 = 0; c8 < 8; ++c8)
#pragma unroll
      for (int kk = 0; kk < 9; ++kk) {
        const int idx = c8 * 9 + kk;
        const float v = acc[idx >> 2][idx & 3];
        rinv[kk] += v * v;
      }
#pragma unroll
    for (int kk = 0; kk < 9; ++kk) {
      float s = rinv[kk];
      s += __shfl_xor(s, 16);
      s += __shfl_xor(s, 32);
      rinv[kk] = rsqrtf(fmaxf(s, 1e-24f));  // == 1/max(sqrt(s),1e-12)
    }

    // pass B: per tap k one b128 patch read (kk=4 reuses cent), s2/dot
    // accumulated per c8; k-norm applied in the epilogue.
    float s2[8], dot[8];
#pragma unroll
    for (int c8 = 0; c8 < 8; ++c8) { s2[c8] = 0.f; dot[c8] = 0.f; }
#pragma unroll
    for (int kk = 0; kk < 9; ++kk) {
      const int kh = kk / 3, kw = kk - kh * 3;
      const uint4 tp = (kk == 4) ? cent
                                 : *(const uint4*)&xrow2[(kh * 66 + kw + px) * 40 + kq * 8];
      const float rv = rinv[kk];
#pragma unroll
      for (int c8 = 0; c8 < 8; ++c8) {
        const int idx = c8 * 9 + kk;
        const float tv = acc[idx >> 2][idx & 3] * rv;
        s2[c8] += tv * tv;
        const unsigned wd = ((const unsigned*)&tp)[c8 >> 1];
        const float pv = (c8 & 1) ? bfhi(wd) : bflo(wd);
        dot[c8] += tv * pv;
      }
    }

    // epilogue: combine per-c8, add dyn-bias partials, butterfly, store.
    const f32x4 wb0 = *(const f32x4*)&Wb_s[oo * 32 + kq * 8];
    const f32x4 wb1 = *(const f32x4*)&Wb_s[oo * 32 + kq * 8 + 4];
    float oacc = 0.f;
#pragma unroll
    for (int c8 = 0; c8 < 8; ++c8) {
      oacc += rsqrtf(fmaxf(s2[c8], 1e-24f)) * dot[c8];
      const unsigned wd = ((const unsigned*)&cent)[c8 >> 1];
      const float xc = (c8 & 1) ? bfhi(wd) : bflo(wd);
      const float wbv = (c8 < 4) ? wb0[c8] : wb1[c8 - 4];
      oacc += wbv * xc;
    }
    oacc += __shfl_xor(oacc, 16);
    oacc += __shfl_xor(oacc, 32);
    if (kq == 0)
      out[((b * 32 + o) * 64 + h) * 64 + px] = oacc + bias2[oo];
  }
}

extern "C" void kernel_launch(void* const* d_in, const int* in_sizes, int n_in,
                              void* d_out, int out_size, void* d_ws, size_t ws_size,
                              hipStream_t stream) {
  const float* x  = (const float*)d_in[0];
  const float* Wp = (const float*)d_in[1];
  const float* bp = (const float*)d_in[2];
  float* out = (float*)d_out;
  if (ws_size >= WQ_BYTES) {
    prep_kernel<<<576, 256, 0, stream>>>(Wp, (unsigned*)d_ws);
    dppc9_kernel<true><<<2048, TPB, 0, stream>>>(x, Wp, bp, (const unsigned*)d_ws, out);
  } else {
    dppc9_kernel<false><<<2048, TPB, 0, stream>>>(x, Wp, bp, nullptr, out);
  }
}

// Round 8
// 77.371 us; speedup vs baseline: 1.1097x; 1.0573x over previous
//
#include <hip/hip_runtime.h>

#define TPB 256
#define WQ_BYTES 589824  // 32*18*64*8*2

typedef __attribute__((ext_vector_type(8))) short short8;
typedef __attribute__((ext_vector_type(4))) float f32x4;

__device__ __forceinline__ unsigned f2bf_pk(float a, float b) {
  return ((__float_as_uint(a) + 0x8000u) >> 16) | ((__float_as_uint(b) + 0x8000u) & 0xffff0000u);
}
__device__ __forceinline__ float bflo(unsigned v) { return __uint_as_float(v << 16); }
__device__ __forceinline__ float bfhi(unsigned v) { return __uint_as_float(v & 0xffff0000u); }

// NOTE (session ledger): reductions use __shfl_xor (LDS pipe). permlane
// swaps regressed (hazard wait-states, R4/R5). Per-oo LDS staging of A
// regressed (barrier lockstep, R0/R6). 2048-block split regressed
// (doubled x-prelude, R7). This file = R2 (77.4 us, session best) + two
// strictly-work-reducing micros (cent dedup, vectorized Wb).

// ---- prep: permuted bf16 A-fragment table (row permute makes each lane's
// 18x4 accumulator exactly 8 cin x 9 k for one pixel) ----------------------
__global__ void prep_kernel(const float* __restrict__ Wp, unsigned* __restrict__ Wq) {
  int idx = blockIdx.x * blockDim.x + threadIdx.x;  // 147456 u32
  if (idx >= 32 * 18 * 64 * 4) return;
  int j2   = idx & 3;
  int lane = (idx >> 2) & 63;
  int rt   = (idx >> 8) % 18;
  int o    = (idx >> 8) / 18;
  int m16 = lane & 15, kq = lane >> 4;
  int row = o * 288 + (m16 >> 2) * 72 + rt * 4 + (m16 & 3);
  const float* src = Wp + row * 32 + kq * 8 + j2 * 2;
  Wq[idx] = f2bf_pk(src[0], src[1]);
}

// ---- main: 1024 blocks = 4/CU resident (16 waves/CU). A-fragments read
// directly from global Wq (og == XCD id -> the CU's 16 waves share the same
// 18 KB/oo slice through L1/L2), with sched_barrier(0)-pinned 6-load/6-MFMA
// groups: at most 24 A-VGPRs in flight (R1's unconstrained hoist of all 18
// loads spilled: WRITE_SIZE 57 MB scratch). After the single prelude
// barrier, waves run fully independently — no per-oo barriers.
template <bool USE_WQ>
__global__ __launch_bounds__(TPB, 4) void dppc9_kernel(
    const float* __restrict__ x, const float* __restrict__ Wp,
    const float* __restrict__ bp, const unsigned* __restrict__ Wq,
    float* __restrict__ out) {
  // [r 0..2][ww 0..65][c 0..31 pad40], bf16; stride 40 shorts = 80 B
  __shared__ __align__(16) unsigned short xrow2[3 * 66 * 40];   // 15840 B
  __shared__ __align__(16) float bp_s[4 * 288];                 // 4608 B
  __shared__ __align__(16) float Wb_s[4 * 32];                  // 512 B
  __shared__ float bias4[4];

  const int tid = threadIdx.x;
  const int bid = blockIdx.x;
  const int og  = bid & 7;      // couts og*4 .. og*4+3  (== XCD id)
  const int t   = bid >> 3;
  const int b   = t >> 6;
  const int h   = t & 63;

  const char* wq_g = (const char*)Wq + (size_t)(og * 4) * 18432;

  // prelude: side-halo zero words (disjoint from interior) + interior stage
  for (int i = tid; i < 120; i += TPB) {      // 6 (r,ww-halo) slots x 20 words
    int p = i / 20, w = i % 20;
    ((unsigned*)xrow2)[(((p >> 1) * 66 + ((p & 1) ? 65 : 0)) * 20) + w] = 0;
  }
  for (int i = tid; i < 1536; i += TPB) {     // r(3) x c4(8) x px(64)
    int px_ = i & 63, c4 = (i >> 6) & 7, r = i >> 9;
    int hh = h - 1 + r;
    unsigned w0 = 0, w1 = 0;
    if ((unsigned)hh < 64u) {
      const float* xp = x + ((b * 32 + c4 * 4) * 64 + hh) * 64 + px_;
      float f0 = xp[0], f1 = xp[4096], f2 = xp[8192], f3 = xp[12288];
      w0 = f2bf_pk(f0, f1);
      w1 = f2bf_pk(f2, f3);
    }
    uint2* dst = (uint2*)&xrow2[(r * 66 + 1 + px_) * 40 + c4 * 4];
    *dst = make_uint2(w0, w1);
  }
  for (int i = tid; i < 1152; i += TPB) bp_s[i] = bp[og * 1152 + i];
  if (tid < 128) Wb_s[tid] = Wp[(9216 + og * 4 + (tid >> 5)) * 32 + (tid & 31)];
  if (tid < 4) bias4[tid] = bp[9216 + og * 4 + tid];
  __syncthreads();   // the ONLY barrier

  const int lane = tid & 63;
  const int wv   = tid >> 6;
  const int m16  = lane & 15, kq = lane >> 4;
  const int px   = wv * 16 + m16;

#pragma unroll 1
  for (int oo = 0; oo < 4; ++oo) {
    const int o = og * 4 + oo;

    // one b128 read serves: MFMA B-fragment, pass-B kk=4 tap, epilogue
    // center tap (all the same 16 B of xrow2).
    const uint4 cent = *(const uint4*)&xrow2[(66 + 1 + px) * 40 + kq * 8];
    const short8 bfrag = *(const short8*)&cent;

    // phase 1: 18 MFMAs; strict 6-load / 6-MFMA groups pinned by
    // sched_barrier(0) on both sides.
    f32x4 acc[18];
    if (USE_WQ) {
      const char* ap = wq_g + ((oo * 1152 + lane) << 4);
#pragma unroll
      for (int g = 0; g < 3; ++g) {
        short8 a6[6];
#pragma unroll
        for (int j = 0; j < 6; ++j)
          a6[j] = *(const short8*)(ap + (((g * 6 + j) << 10)));
        __builtin_amdgcn_sched_barrier(0);
#pragma unroll
        for (int j = 0; j < 6; ++j) {
          const int rt = g * 6 + j;
          const f32x4 bb = *(const f32x4*)&bp_s[oo * 288 + kq * 72 + rt * 4];
          acc[rt] = __builtin_amdgcn_mfma_f32_16x16x32_bf16(a6[j], bfrag, bb, 0, 0, 0);
        }
        __builtin_amdgcn_sched_barrier(0);
      }
    } else {
      const float* ab = Wp + (o * 288 + (m16 >> 2) * 72 + (m16 & 3)) * 32 + kq * 8;
#pragma unroll
      for (int rt = 0; rt < 18; ++rt) {
        const float* ap = ab + rt * 4 * 32;
        float4 a0 = *(const float4*)ap;
        float4 a1 = *(const float4*)(ap + 4);
        union { short8 v; unsigned u[4]; } af;
        af.u[0] = f2bf_pk(a0.x, a0.y);
        af.u[1] = f2bf_pk(a0.z, a0.w);
        af.u[2] = f2bf_pk(a1.x, a1.y);
        af.u[3] = f2bf_pk(a1.z, a1.w);
        const f32x4 bb = *(const f32x4*)&bp_s[oo * 288 + kq * 72 + rt * 4];
        acc[rt] = __builtin_amdgcn_mfma_f32_16x16x32_bf16(af.v, bfrag, bb, 0, 0, 0);
      }
    }

    // cin-norm denominators: local partial + butterfly across kq (bits 4,5)
    float rinv[9];
#pragma unroll
    for (int kk = 0; kk < 9; ++kk) rinv[kk] = 0.f;
#pragma unroll
    for (int c8 = 0; c8 < 8; ++c8)
#pragma unroll
      for (int kk = 0; kk < 9; ++kk) {
        const int idx = c8 * 9 + kk;
        const float v = acc[idx >> 2][idx & 3];
        rinv[kk] += v * v;
      }
#pragma unroll
    for (int kk = 0; kk < 9; ++kk) {
      float s = rinv[kk];
      s += __shfl_xor(s, 16);
      s += __shfl_xor(s, 32);
      rinv[kk] = rsqrtf(fmaxf(s, 1e-24f));  // == 1/max(sqrt(s),1e-12)
    }

    // pass B: per tap k one b128 patch read (kk=4 reuses cent), s2/dot
    // accumulated per c8; k-norm applied in the epilogue.
    float s2[8], dot[8];
#pragma unroll
    for (int c8 = 0; c8 < 8; ++c8) { s2[c8] = 0.f; dot[c8] = 0.f; }
#pragma unroll
    for (int kk = 0; kk < 9; ++kk) {
      const int kh = kk / 3, kw = kk - kh * 3;
      const uint4 tp = (kk == 4) ? cent
                                 : *(const uint4*)&xrow2[(kh * 66 + kw + px) * 40 + kq * 8];
      const float rv = rinv[kk];
#pragma unroll
      for (int c8 = 0; c8 < 8; ++c8) {
        const int idx = c8 * 9 + kk;
        const float tv = acc[idx >> 2][idx & 3] * rv;
        s2[c8] += tv * tv;
        const unsigned wd = ((const unsigned*)&tp)[c8 >> 1];
        const float pv = (c8 & 1) ? bfhi(wd) : bflo(wd);
        dot[c8] += tv * pv;
      }
    }

    // epilogue: combine per-c8, add dyn-bias partials, butterfly, store.
    const f32x4 wb0 = *(const f32x4*)&Wb_s[oo * 32 + kq * 8];
    const f32x4 wb1 = *(const f32x4*)&Wb_s[oo * 32 + kq * 8 + 4];
    float oacc = 0.f;
#pragma unroll
    for (int c8 = 0; c8 < 8; ++c8) {
      oacc += rsqrtf(fmaxf(s2[c8], 1e-24f)) * dot[c8];
      const unsigned wd = ((const unsigned*)&cent)[c8 >> 1];
      const float xc = (c8 & 1) ? bfhi(wd) : bflo(wd);
      const float wbv = (c8 < 4) ? wb0[c8] : wb1[c8 - 4];
      oacc += wbv * xc;
    }
    oacc += __shfl_xor(oacc, 16);
    oacc += __shfl_xor(oacc, 32);
    if (kq == 0)
      out[((b * 32 + o) * 64 + h) * 64 + px] = oacc + bias4[oo];
  }
}

extern "C" void kernel_launch(void* const* d_in, const int* in_sizes, int n_in,
                              void* d_out, int out_size, void* d_ws, size_t ws_size,
                              hipStream_t stream) {
  const float* x  = (const float*)d_in[0];
  const float* Wp = (const float*)d_in[1];
  const float* bp = (const float*)d_in[2];
  float* out = (float*)d_out;
  if (ws_size >= WQ_BYTES) {
    prep_kernel<<<576, 256, 0, stream>>>(Wp, (unsigned*)d_ws);
    dppc9_kernel<true><<<1024, TPB, 0, stream>>>(x, Wp, bp, (const unsigned*)d_ws, out);
  } else {
    dppc9_kernel<false><<<1024, TPB, 0, stream>>>(x, Wp, bp, nullptr, out);
  }
}